// Round 4
// baseline (125.028 us; speedup 1.0000x reference)
//
#include <hip/hip_runtime.h>

#define NUM_BINS 256
#define PER_HIST 786432            // 3*512*512 elements per batch item
#define BATCH 16
#define NHIST 32                   // 2 inputs * 16 batch items
#define CHUNKS 64                  // blocks per histogram
#define THREADS 256
#define ELEMS_PER_BLOCK (PER_HIST / CHUNKS)   // 12288
#define VEC_PER_BLOCK (ELEMS_PER_BLOCK / 4)   // 3072 float4
#define ITERS (VEC_PER_BLOCK / THREADS)       // 12

typedef float floatx4 __attribute__((ext_vector_type(4)));

// ws layout: [0, 2MB) per-block partial hists  part[hid][chunk][bin] (uint)
//            [2MB, 2MB+128) per-batch int64 EMD numerators
#define PART_WORDS (NHIST * CHUNKS * NUM_BINS)    // 524288

__global__ __launch_bounds__(THREADS) void hist_kernel(const float* __restrict__ im1,
                                                       const float* __restrict__ im2,
                                                       unsigned int* __restrict__ part) {
    // per-wave sub-histograms: 4 waves * 256 bins (4 KB LDS)
    __shared__ unsigned int lh[4][NUM_BINS];
    const int t = threadIdx.x;
    const int w = t >> 6;

    #pragma unroll
    for (int i = 0; i < 4; ++i) lh[i][t] = 0u;
    __syncthreads();

    const int hid = blockIdx.y;                 // 0..31
    const float* src = (hid < BATCH) ? im1 : im2;
    const int batch = hid & (BATCH - 1);
    const floatx4* p = (const floatx4*)(src + (size_t)batch * PER_HIST
                                            + (size_t)blockIdx.x * ELEMS_PER_BLOCK);

    // replicate reference f32 math exactly: idx = floor((x*255) * (256/255))
    const float c255 = 255.0f;
    const float scale = (float)NUM_BINS / 255.0f;

    #pragma unroll
    for (int i = 0; i < ITERS; ++i) {
        floatx4 v = __builtin_nontemporal_load(&p[i * THREADS + t]);
        #pragma unroll
        for (int j = 0; j < 4; ++j) {
            float x = v[j] * c255;
            float tt = x * scale;
            int idx = (int)tt;                  // x >= 0 so trunc == floor
            idx = idx > (NUM_BINS - 1) ? (NUM_BINS - 1) : idx;
            idx = idx < 0 ? 0 : idx;
            atomicAdd(&lh[w][idx], 1u);
        }
    }
    __syncthreads();

    // plain per-block partial store — no zeroing, no global atomics
    unsigned int sum = lh[0][t] + lh[1][t] + lh[2][t] + lh[3][t];
    part[((size_t)hid * CHUNKS + blockIdx.x) * NUM_BINS + t] = sum;
}

// one block per batch: reduce 64 partials for both hists, scan, abs-sum
__global__ __launch_bounds__(THREADS) void emd_batch_kernel(const unsigned int* __restrict__ part,
                                                            long long* __restrict__ bemd) {
    __shared__ int wave_sums[4];
    const int t = threadIdx.x;                 // = bin
    const int w = t >> 6;
    const int lane = t & 63;
    const int b = blockIdx.x;                  // batch 0..15

    const unsigned int* p1 = part + (size_t)b * CHUNKS * NUM_BINS;
    const unsigned int* p2 = part + (size_t)(BATCH + b) * CHUNKS * NUM_BINS;

    int s1 = 0, s2 = 0;
    #pragma unroll 8
    for (int c = 0; c < CHUNKS; ++c) {
        s1 += (int)p1[c * NUM_BINS + t];       // coalesced: consecutive t -> consecutive words
        s2 += (int)p2[c * NUM_BINS + t];
    }
    int d = s1 - s2;                           // exact integer count diff

    // inclusive shuffle scan within wave
    int s = d;
    #pragma unroll
    for (int off = 1; off < 64; off <<= 1) {
        int v = __shfl_up(s, off, 64);
        if (lane >= off) s += v;
    }
    if (lane == 63) wave_sums[w] = s;
    __syncthreads();

    int wave_off = 0;
    #pragma unroll
    for (int i = 0; i < 4; ++i) wave_off += (i < w) ? wave_sums[i] : 0;
    int cdf = wave_off + s;                    // CDF diff * PER_HIST, exact
    int a = cdf < 0 ? -cdf : cdf;

    // block reduce of |cdf|: wave shuffle reduce + LDS
    #pragma unroll
    for (int off = 32; off > 0; off >>= 1) a += __shfl_xor(a, off, 64);
    __syncthreads();                           // reuse wave_sums
    if (lane == 0) wave_sums[w] = a;
    __syncthreads();
    if (t == 0) {
        long long tot = (long long)wave_sums[0] + wave_sums[1] + wave_sums[2] + wave_sums[3];
        bemd[b] = tot;
    }
}

__global__ __launch_bounds__(64) void finalize_kernel(const long long* __restrict__ bemd,
                                                      float* __restrict__ out) {
    const int lane = threadIdx.x;
    long long v = (lane < BATCH) ? bemd[lane] : 0LL;
    #pragma unroll
    for (int off = 32; off > 0; off >>= 1) v += __shfl_xor(v, off, 64);
    if (lane == 0) {
        double total = (double)v / (double)PER_HIST / (double)NUM_BINS / 3.0;
        out[0] = (float)total;
    }
}

extern "C" void kernel_launch(void* const* d_in, const int* in_sizes, int n_in,
                              void* d_out, int out_size, void* d_ws, size_t ws_size,
                              hipStream_t stream) {
    const float* im1 = (const float*)d_in[0];
    const float* im2 = (const float*)d_in[1];
    unsigned int* part = (unsigned int*)d_ws;                 // 2 MB partials
    long long* bemd = (long long*)((char*)d_ws + PART_WORDS * sizeof(unsigned int));
    float* out = (float*)d_out;

    dim3 grid(CHUNKS, NHIST);
    hist_kernel<<<grid, THREADS, 0, stream>>>(im1, im2, part);

    emd_batch_kernel<<<BATCH, THREADS, 0, stream>>>(part, bemd);

    finalize_kernel<<<1, 64, 0, stream>>>(bemd, out);
}

// Round 5
// 120.264 us; speedup vs baseline: 1.0396x; 1.0396x over previous
//
#include <hip/hip_runtime.h>

#define NUM_BINS 256
#define PER_HIST 786432            // 3*512*512 elements per batch item
#define BATCH 16
#define NHIST 32                   // 2 inputs * 16 batch items
#define CHUNKS 64                  // blocks per histogram
#define THREADS 256
#define ELEMS_PER_BLOCK (PER_HIST / CHUNKS)   // 12288
#define VEC_PER_BLOCK (ELEMS_PER_BLOCK / 4)   // 3072 float4
#define ITERS (VEC_PER_BLOCK / THREADS)       // 12

typedef float floatx4 __attribute__((ext_vector_type(4)));

__global__ void zero_ws_kernel(unsigned int* __restrict__ ws) {
    ws[blockIdx.x * blockDim.x + threadIdx.x] = 0u;
}

__global__ __launch_bounds__(THREADS) void hist_kernel(const float* __restrict__ im1,
                                                       const float* __restrict__ im2,
                                                       unsigned int* __restrict__ hist) {
    // 8 sub-histograms: 4 waves x 2 (lane parity) x 256 bins (8 KB LDS).
    // Parity split halves same-address atomic RMW serialization within a wave.
    __shared__ unsigned int lh[4][2][NUM_BINS];
    const int t = threadIdx.x;
    const int w = t >> 6;
    const int par = t & 1;

    #pragma unroll
    for (int i = 0; i < 4; ++i) { lh[i][0][t] = 0u; lh[i][1][t] = 0u; }
    __syncthreads();

    const int hid = blockIdx.y;                 // 0..31
    const float* src = (hid < BATCH) ? im1 : im2;
    const int batch = hid & (BATCH - 1);
    const floatx4* p = (const floatx4*)(src + (size_t)batch * PER_HIST
                                            + (size_t)blockIdx.x * ELEMS_PER_BLOCK);

    // replicate reference f32 math exactly: idx = floor((x*255) * (256/255))
    const float c255 = 255.0f;
    const float scale = (float)NUM_BINS / 255.0f;

    unsigned int* mh = lh[w][par];

    #pragma unroll
    for (int i = 0; i < ITERS; ++i) {
        floatx4 v = __builtin_nontemporal_load(&p[i * THREADS + t]);
        #pragma unroll
        for (int j = 0; j < 4; ++j) {
            float x = v[j] * c255;
            float tt = x * scale;
            int idx = (int)tt;                  // x >= 0 so trunc == floor, idx >= 0 always
            idx = idx > (NUM_BINS - 1) ? (NUM_BINS - 1) : idx;
            atomicAdd(&mh[idx], 1u);
        }
    }
    __syncthreads();

    unsigned int sum = lh[0][0][t] + lh[0][1][t] + lh[1][0][t] + lh[1][1][t]
                     + lh[2][0][t] + lh[2][1][t] + lh[3][0][t] + lh[3][1][t];
    atomicAdd(&hist[hid * NUM_BINS + t], sum);
}

// one wave per batch, shuffle-based scan — no per-round barriers
__global__ __launch_bounds__(1024) void emd_kernel(const unsigned int* __restrict__ hist,
                                                   float* __restrict__ out) {
    __shared__ int batch_emd[BATCH];
    const int t = threadIdx.x;
    const int w = t >> 6;          // wave id = batch id (0..15)
    const int lane = t & 63;       // lane owns bins 4*lane .. 4*lane+3

    const uint4* h1 = (const uint4*)(hist + w * NUM_BINS);
    const uint4* h2 = (const uint4*)(hist + (BATCH + w) * NUM_BINS);
    uint4 a = h1[lane];
    uint4 b = h2[lane];

    // exact integer count diffs
    int d0 = (int)a.x - (int)b.x;
    int d1 = (int)a.y - (int)b.y;
    int d2 = (int)a.z - (int)b.z;
    int d3 = (int)a.w - (int)b.w;

    // in-lane inclusive prefix
    int p0 = d0;
    int p1 = p0 + d1;
    int p2 = p1 + d2;
    int p3 = p2 + d3;

    // 64-lane inclusive scan of lane sums (p3)
    int s = p3;
    #pragma unroll
    for (int off = 1; off < 64; off <<= 1) {
        int v = __shfl_up(s, off, 64);
        if (lane >= off) s += v;
    }
    int excl = s - p3;   // exclusive prefix for this lane

    int c0 = excl + p0, c1 = excl + p1, c2 = excl + p2, c3 = excl + p3;
    int aa = (c0 < 0 ? -c0 : c0) + (c1 < 0 ? -c1 : c1)
           + (c2 < 0 ? -c2 : c2) + (c3 < 0 ? -c3 : c3);

    // wave reduce; max 256*786432 ≈ 2.01e8 < 2^31, no overflow
    #pragma unroll
    for (int off = 32; off > 0; off >>= 1) aa += __shfl_xor(aa, off, 64);

    if (lane == 0) batch_emd[w] = aa;
    __syncthreads();

    if (t == 0) {
        long long acc = 0;
        #pragma unroll
        for (int i = 0; i < BATCH; ++i) acc += (long long)batch_emd[i];
        double total = (double)acc / (double)PER_HIST / (double)NUM_BINS / 3.0;
        out[0] = (float)total;
    }
}

extern "C" void kernel_launch(void* const* d_in, const int* in_sizes, int n_in,
                              void* d_out, int out_size, void* d_ws, size_t ws_size,
                              hipStream_t stream) {
    const float* im1 = (const float*)d_in[0];
    const float* im2 = (const float*)d_in[1];
    unsigned int* hist = (unsigned int*)d_ws;   // 32 * 256 * 4 B = 32 KB
    float* out = (float*)d_out;

    zero_ws_kernel<<<NHIST * NUM_BINS / THREADS, THREADS, 0, stream>>>(hist);

    dim3 grid(CHUNKS, NHIST);
    hist_kernel<<<grid, THREADS, 0, stream>>>(im1, im2, hist);

    emd_kernel<<<1, 1024, 0, stream>>>(hist, out);
}